// Round 6
// baseline (131.109 us; speedup 1.0000x reference)
//
#include <hip/hip_runtime.h>
#include <math.h>

#define NB 32
#define CC 64
#define LL 1024
#define EPS 1e-6f
#define SCALE 14.42695040888963f   // 10*log2(e): exp(10*s) == exp2(SCALE*s)

typedef __attribute__((ext_vector_type(8))) __bf16 bf16x8;
typedef __attribute__((ext_vector_type(4))) float f32x4;

// ws byte layout:
//   At      @ 0         (4 MB)   bf16 [32][1024][64]  rgb, normalized*SCALE, [l][c]
//   Bt      @ 4194304   (4 MB)   bf16 [32][1024][64]  ir, normalized, [l][c]
//   row_sum @ 8388608   (128 KB) f32[32768]
//   col_sum @ 8519680   (128 KB) f32[32768]
//   row_pk  @ 8650752   (128 KB) u32[32768]  (expbits&~1023)|(1023-j)
//   col_pk  @ 8781824   (128 KB) u32[32768]  (expbits&~1023)|(1023-i)
//   partial @ 8912896   (256 B)  f32[64] loss partials
// No zero-init: every stats word is direct-stored exactly once.

__global__ __launch_bounds__(256) void transpose_norm_kernel(
        const float* __restrict__ rgb, const float* __restrict__ ir,
        __bf16* __restrict__ At, __bf16* __restrict__ Bt) {
    __shared__ float tile[64][65];
    __shared__ float red[4][64];
    __shared__ float rn[64];

    const int t   = threadIdx.x;
    const int blk = blockIdx.x;
    const int in  = blk >> 9;
    const int b   = (blk >> 4) & 31;
    const int l0  = (blk & 15) << 6;
    const float* src = in ? ir : rgb;
    __bf16*      dst = in ? Bt : At;
    const float  sc  = in ? 1.0f : SCALE;   // fold exp2 prescale into rgb side

    const int ll = t & 63, cg = t >> 6;
    const float* sp = src + ((size_t)b << 16) + l0 + ll;
#pragma unroll
    for (int u = 0; u < 16; ++u) {
        int c = cg * 16 + u;
        tile[c][ll] = sp[(size_t)c << 10];
    }
    __syncthreads();

    float ssq = 0.f;
#pragma unroll
    for (int u = 0; u < 16; ++u) {
        float v = tile[cg * 16 + u][ll];
        ssq = fmaf(v, v, ssq);
    }
    red[cg][ll] = ssq;
    __syncthreads();
    if (t < 64) {
        float s = red[0][t] + red[1][t] + red[2][t] + red[3][t];
        rn[t] = sc / fmaxf(sqrtf(s), 1e-12f);
    }
    __syncthreads();

    const int lw  = t >> 2;
    const int cg2 = t & 3;
    const float r = rn[lw];
    bf16x8 v0, v1;
#pragma unroll
    for (int u = 0; u < 8; ++u)
        v0[u] = (__bf16)(tile[cg2 * 16 + u][lw] * r);
#pragma unroll
    for (int u = 0; u < 8; ++u)
        v1[u] = (__bf16)(tile[cg2 * 16 + 8 + u][lw] * r);
    size_t base = ((((size_t)b << 10) + l0 + lw) << 6) + cg2 * 16;
    *(bf16x8*)(dst + base)     = v0;
    *(bf16x8*)(dst + base + 8) = v1;
}

// Grid 1024 = dir(2) x batch(32) x itile(16). Wave w owns rows [i0+16w,+16) x
// all 1024 cols of S (dir 0) or S^T (dir 1; bitwise-identical values). Stats
// complete in-wave: one butterfly, direct stores, zero atomics/barriers/init.
// r5 lesson (62.5 us, 2.3K cyc/iter): only 2 outstanding loads exposed full
// L2/L3 latency. Fix: 8-deep register prefetch ring -> 16 outstanding
// dwordx4/wave; no barriers anywhere, so the compiler emits partial vmcnt
// waits (AITER-style), covering ~700-cyc latency with ~8 iters of work.
__global__ __launch_bounds__(256, 4) void gemm_stats_kernel(
        const __bf16* __restrict__ At, const __bf16* __restrict__ Bt,
        float* __restrict__ row_sum, unsigned* __restrict__ row_pk,
        float* __restrict__ col_sum, unsigned* __restrict__ col_pk) {
    const int t   = threadIdx.x;
    const int blk = blockIdx.x;
    const int dir = blk >> 9;
    const int bb  = (blk >> 4) & 31;
    const int i0  = (blk & 15) << 6;
    const int w = t >> 6, lane = t & 63;
    const int m = lane & 15, q = lane >> 4;

    const __bf16* Aarr = dir ? Bt : At;
    const __bf16* Barr = dir ? At : Bt;
    float*    osum = dir ? col_sum : row_sum;
    unsigned* opk  = dir ? col_pk  : row_pk;

    const size_t bbase = (size_t)bb << 16;

    // A fragments (held all kernel): row = i0+16w+m, k = kb*32 + q*8.
    const __bf16* Ap = Aarr + bbase + ((size_t)(i0 + 16 * w + m) << 6) + q * 8;
    const bf16x8 a0 = *(const bf16x8*)(Ap);
    const bf16x8 a1 = *(const bf16x8*)(Ap + 32);

    const __bf16* Bp = Barr + bbase + ((size_t)m << 6) + q * 8;

    // ---- 8-deep prefetch ring ----
    bf16x8 buf0[8], buf1[8];
#pragma unroll
    for (int p = 0; p < 8; ++p) {
        const __bf16* bp = Bp + ((size_t)p << 10);
        buf0[p] = *(const bf16x8*)(bp);
        buf1[p] = *(const bf16x8*)(bp + 32);
    }

    float    rsum[4] = {0.f, 0.f, 0.f, 0.f};
    unsigned rpk[4]  = {0u, 0u, 0u, 0u};

    // Main: 7 outer iters with prefetch (ct0 = 0..48), then 8-iter tail.
    for (int ct0 = 0; ct0 < 56; ct0 += 8) {
#pragma unroll
        for (int u = 0; u < 8; ++u) {
            const int ct = ct0 + u;
            bf16x8 b0 = buf0[u], b1 = buf1[u];
            {   // prefetch ct+8 into the slot just vacated
                const __bf16* bp = Bp + ((size_t)(ct + 8) << 10);
                buf0[u] = *(const bf16x8*)(bp);
                buf1[u] = *(const bf16x8*)(bp + 32);
            }
            f32x4 acc = (f32x4){0.f, 0.f, 0.f, 0.f};
            acc = __builtin_amdgcn_mfma_f32_16x16x32_bf16(a0, b0, acc, 0, 0, 0);
            acc = __builtin_amdgcn_mfma_f32_16x16x32_bf16(a1, b1, acc, 0, 0, 0);
            // C/D layout (verified r2-r5): row = i0+16w+4q+r, col = 16ct+m.
            unsigned jinv = 1023u - (unsigned)((ct << 4) + m);
#pragma unroll
            for (int r = 0; r < 4; ++r) {
                float e = __builtin_amdgcn_exp2f(acc[r]);   // SCALE folded into At
                unsigned p = (__float_as_uint(e) & 0xFFFFFC00u) | jinv;
                rsum[r] += e;
                if (p > rpk[r]) rpk[r] = p;
            }
        }
    }
#pragma unroll
    for (int u = 0; u < 8; ++u) {
        const int ct = 56 + u;
        bf16x8 b0 = buf0[u], b1 = buf1[u];
        f32x4 acc = (f32x4){0.f, 0.f, 0.f, 0.f};
        acc = __builtin_amdgcn_mfma_f32_16x16x32_bf16(a0, b0, acc, 0, 0, 0);
        acc = __builtin_amdgcn_mfma_f32_16x16x32_bf16(a1, b1, acc, 0, 0, 0);
        unsigned jinv = 1023u - (unsigned)((ct << 4) + m);
#pragma unroll
        for (int r = 0; r < 4; ++r) {
            float e = __builtin_amdgcn_exp2f(acc[r]);
            unsigned p = (__float_as_uint(e) & 0xFFFFFC00u) | jinv;
            rsum[r] += e;
            if (p > rpk[r]) rpk[r] = p;
        }
    }

    // One butterfly over the 16 m-lanes (xor 1,2,4,8) — stats complete.
#pragma unroll
    for (int s = 1; s < 16; s <<= 1) {
#pragma unroll
        for (int r = 0; r < 4; ++r) {
            rsum[r] += __shfl_xor(rsum[r], s, 64);
            unsigned o = (unsigned)__shfl_xor((int)rpk[r], s, 64);
            if (o > rpk[r]) rpk[r] = o;
        }
    }
    if (m == 0) {
#pragma unroll
        for (int r = 0; r < 4; ++r) {
            int idx = (bb << 10) + i0 + 16 * w + 4 * q + r;
            osum[idx] = rsum[r];
            opk[idx]  = rpk[r];
        }
    }
}

// Reference broadcasting: trailing /(sum+EPS) factors are indexed by ELEMENT
// position, not by argmax. Writes per-block partials (no atomics, no init).
__global__ __launch_bounds__(256) void loss_kernel2(
        const float* __restrict__ row_sum, const unsigned* __restrict__ row_pk,
        const float* __restrict__ col_sum, const unsigned* __restrict__ col_pk,
        float* __restrict__ partial) {
    int t = blockIdx.x * 256 + threadIdx.x;
    float acc = 0.f;
#pragma unroll
    for (int it = 0; it < 4; ++it) {
        int p = t + it * 16384;
        if (p < NB * LL) {
            unsigned pk2 = row_pk[p];
            float m2 = __uint_as_float(pk2 & 0xFFFFFC00u);
            int j = 1023 - (int)(pk2 & 1023u);
            float s2 = row_sum[p];
            float s1 = col_sum[p];
            unsigned pk1 = col_pk[(p & ~1023) + j];
            float m1 = __uint_as_float(pk1 & 0xFFFFFC00u);
            acc += logf((m2 / (s2 + EPS)) * (m1 / (s1 + EPS)));
        } else {
            int p2 = p - NB * LL;
            unsigned pk1 = col_pk[p2];
            float m1 = __uint_as_float(pk1 & 0xFFFFFC00u);
            int i = 1023 - (int)(pk1 & 1023u);
            float s1 = col_sum[p2];
            float s2 = row_sum[p2];
            unsigned pk2 = row_pk[(p2 & ~1023) + i];
            float m2 = __uint_as_float(pk2 & 0xFFFFFC00u);
            acc += logf((m1 / (s1 + EPS)) * (m2 / (s2 + EPS)));
        }
    }
#pragma unroll
    for (int off = 32; off > 0; off >>= 1) acc += __shfl_down(acc, off, 64);
    __shared__ float wsum[4];
    int lane = threadIdx.x & 63, w = threadIdx.x >> 6;
    if (lane == 0) wsum[w] = acc;
    __syncthreads();
    if (threadIdx.x == 0)
        partial[blockIdx.x] = wsum[0] + wsum[1] + wsum[2] + wsum[3];
}

__global__ void finalize_kernel(const float* __restrict__ partial,
                                float* __restrict__ out) {
    float v = partial[threadIdx.x];
#pragma unroll
    for (int off = 32; off > 0; off >>= 1) v += __shfl_down(v, off, 64);
    if (threadIdx.x == 0) out[0] = -v / (float)(2 * NB * LL);
}

extern "C" void kernel_launch(void* const* d_in, const int* in_sizes, int n_in,
                              void* d_out, int out_size, void* d_ws, size_t ws_size,
                              hipStream_t stream) {
    const float* rgb = (const float*)d_in[0];
    const float* ir  = (const float*)d_in[1];
    char* wsb = (char*)d_ws;

    __bf16*   At      = (__bf16*)(wsb);
    __bf16*   Bt      = (__bf16*)(wsb + 4194304);
    float*    row_sum = (float*)(wsb + 8388608);
    float*    col_sum = (float*)(wsb + 8519680);
    unsigned* row_pk  = (unsigned*)(wsb + 8650752);
    unsigned* col_pk  = (unsigned*)(wsb + 8781824);
    float*    partial = (float*)(wsb + 8912896);

    transpose_norm_kernel<<<1024, 256, 0, stream>>>(rgb, ir, At, Bt);
    gemm_stats_kernel<<<1024, 256, 0, stream>>>(At, Bt, row_sum, row_pk,
                                                col_sum, col_pk);
    loss_kernel2<<<64, 256, 0, stream>>>(row_sum, row_pk, col_sum, col_pk, partial);
    finalize_kernel<<<1, 64, 0, stream>>>(partial, (float*)d_out);
}

// Round 7
// 89.682 us; speedup vs baseline: 1.4619x; 1.4619x over previous
//
#include <hip/hip_runtime.h>
#include <math.h>

#define NB 32
#define CC 64
#define LL 1024
#define EPS 1e-6f
#define SCALE 14.42695040888963f   // 10*log2(e): exp(10*s) == exp2(SCALE*s)

typedef __attribute__((ext_vector_type(8))) __bf16 bf16x8;
typedef __attribute__((ext_vector_type(4))) float f32x4;

#define GLB(p) ((__attribute__((address_space(1))) void*)(p))
#define LDS(p) ((__attribute__((address_space(3))) void*)(p))

// ws byte layout:
//   At      @ 0         (4 MB)   bf16 [32][1024][64]  rgb, normalized*SCALE, [l][c]
//   Bt      @ 4194304   (4 MB)   bf16 [32][1024][64]  ir, normalized, [l][c]
//   row_sum @ 8388608   (128 KB) f32[32768]
//   col_sum @ 8519680   (128 KB) f32[32768]
//   row_pk  @ 8650752   (128 KB) u32[32768]  (expbits&~1023)|(1023-j)
//   col_pk  @ 8781824   (128 KB) u32[32768]  (expbits&~1023)|(1023-i)
//   partial @ 8912896   (256 B)  f32[64] loss partials
// No zero-init: every stats word is direct-stored exactly once.

__global__ __launch_bounds__(256) void transpose_norm_kernel(
        const float* __restrict__ rgb, const float* __restrict__ ir,
        __bf16* __restrict__ At, __bf16* __restrict__ Bt) {
    __shared__ float tile[64][65];
    __shared__ float red[4][64];
    __shared__ float rn[64];

    const int t   = threadIdx.x;
    const int blk = blockIdx.x;
    const int in  = blk >> 9;
    const int b   = (blk >> 4) & 31;
    const int l0  = (blk & 15) << 6;
    const float* src = in ? ir : rgb;
    __bf16*      dst = in ? Bt : At;
    const float  sc  = in ? 1.0f : SCALE;   // fold exp2 prescale into rgb side

    const int ll = t & 63, cg = t >> 6;
    const float* sp = src + ((size_t)b << 16) + l0 + ll;
#pragma unroll
    for (int u = 0; u < 16; ++u) {
        int c = cg * 16 + u;
        tile[c][ll] = sp[(size_t)c << 10];
    }
    __syncthreads();

    float ssq = 0.f;
#pragma unroll
    for (int u = 0; u < 16; ++u) {
        float v = tile[cg * 16 + u][ll];
        ssq = fmaf(v, v, ssq);
    }
    red[cg][ll] = ssq;
    __syncthreads();
    if (t < 64) {
        float s = red[0][t] + red[1][t] + red[2][t] + red[3][t];
        rn[t] = sc / fmaxf(sqrtf(s), 1e-12f);
    }
    __syncthreads();

    const int lw  = t >> 2;
    const int cg2 = t & 3;
    const float r = rn[lw];
    bf16x8 v0, v1;
#pragma unroll
    for (int u = 0; u < 8; ++u)
        v0[u] = (__bf16)(tile[cg2 * 16 + u][lw] * r);
#pragma unroll
    for (int u = 0; u < 8; ++u)
        v1[u] = (__bf16)(tile[cg2 * 16 + 8 + u][lw] * r);
    size_t base = ((((size_t)b << 10) + l0 + lw) << 6) + cg2 * 16;
    *(bf16x8*)(dst + base)     = v0;
    *(bf16x8*)(dst + base + 8) = v1;
}

// Grid 1024 = dir(2) x batch(32) x itile(16). Wave w owns rows [i0+16w,+16) x
// all 1024 cols of S (dir 0) or S^T (dir 1; bitwise-identical values). Stats
// complete in-wave: one butterfly, direct stores, zero atomics.
//
// r6 lesson: register prefetch is un-pinnable (compiler sank the ring,
// VGPR=52, still 2 loads in flight, 63 us latency-bound). Fix: async
// global->LDS staging via global_load_lds (side-effecting intrinsic, CANNOT
// be sunk), double-buffered: issue chunk c+1's loads, compute chunk c, then
// one barrier — the vmcnt drain at the barrier is covered by the ~670-cyc
// compute section.
//
// LDS swizzle: global_load_lds forces LDS slot = base + lane*16 (no padding,
// m104). We permute on the GLOBAL side (free gather within each 128-B row):
// segment s of row r lands at slot s^(r&7). Fragment ds_read_b128 then hits
// each bank exactly 8x (the 256-dword/32-bank floor) instead of 16x.
__global__ __launch_bounds__(256, 4) void gemm_stats_kernel(
        const __bf16* __restrict__ At, const __bf16* __restrict__ Bt,
        float* __restrict__ row_sum, unsigned* __restrict__ row_pk,
        float* __restrict__ col_sum, unsigned* __restrict__ col_pk) {
    __shared__ __bf16 Bs[2][8192];   // 2 x 16 KB (128 rows x 64 bf16)

    const int t   = threadIdx.x;
    const int blk = blockIdx.x;
    const int dir = blk >> 9;
    const int bb  = (blk >> 4) & 31;
    const int i0  = (blk & 15) << 6;
    const int w = t >> 6, lane = t & 63;
    const int m = lane & 15, q = lane >> 4;

    const __bf16* Aarr = dir ? Bt : At;
    const __bf16* Barr = dir ? At : Bt;
    float*    osum = dir ? col_sum : row_sum;
    unsigned* opk  = dir ? col_pk  : row_pk;

    const size_t bbase = (size_t)bb << 16;
    const __bf16* Bg = Barr + bbase;

    // A fragments (held all kernel): row = i0+16w+m, k = kb*32 + q*8.
    const __bf16* Ap = Aarr + bbase + ((size_t)(i0 + 16 * w + m) << 6) + q * 8;
    const bf16x8 a0 = *(const bf16x8*)(Ap);
    const bf16x8 a1 = *(const bf16x8*)(Ap + 32);

    // Swizzled fragment read offsets (elements): row lr=16u+m, seg slot
    // s0=q^(m&7) (k 0..7 half), s1=(q^4)^(m&7) (k 32..39 half).
    const int mbase = m * 64;
    const int s0 = (q ^ (m & 7)) << 3;
    const int s1 = ((q ^ 4) ^ (m & 7)) << 3;

    float    rsum[4] = {0.f, 0.f, 0.f, 0.f};
    unsigned rpk[4]  = {0u, 0u, 0u, 0u};

    // Per-thread staging geometry: slot = rho*256+t covers 16 B; row r =
    // slot>>3 (0..127), lds seg = slot&7, global seg sg = (slot&7)^(r&7).
    const int sr = t >> 3;          // row contribution from t (0..31)
    const int ssl = t & 7;          // seg slot from t

    // stage chunk 0 -> Bs[0]
#pragma unroll
    for (int rho = 0; rho < 4; ++rho) {
        int r  = rho * 32 + sr;
        int sg = ssl ^ (r & 7);
        const __bf16* gp = Bg + ((size_t)r << 6) + sg * 8;
        __builtin_amdgcn_global_load_lds(GLB(gp), LDS(&Bs[0][(rho << 11) + (w << 9)]),
                                         16, 0, 0);
    }
    __syncthreads();   // chunk 0 ready

    for (int c = 0; c < 8; ++c) {
        const int cur = c & 1;
        if (c < 7) {   // issue async loads for chunk c+1 into the other buffer
#pragma unroll
            for (int rho = 0; rho < 4; ++rho) {
                int r  = rho * 32 + sr;
                int sg = ssl ^ (r & 7);
                const __bf16* gp = Bg + ((size_t)((c + 1) * 128 + r) << 6) + sg * 8;
                __builtin_amdgcn_global_load_lds(GLB(gp),
                        LDS(&Bs[cur ^ 1][(rho << 11) + (w << 9)]), 16, 0, 0);
            }
        }
        const __bf16* pb0 = &Bs[cur][mbase + s0];
        const __bf16* pb1 = &Bs[cur][mbase + s1];
#pragma unroll
        for (int u = 0; u < 8; ++u) {
            bf16x8 b0 = *(const bf16x8*)(pb0 + (u << 10));
            bf16x8 b1 = *(const bf16x8*)(pb1 + (u << 10));
            f32x4 acc = (f32x4){0.f, 0.f, 0.f, 0.f};
            acc = __builtin_amdgcn_mfma_f32_16x16x32_bf16(a0, b0, acc, 0, 0, 0);
            acc = __builtin_amdgcn_mfma_f32_16x16x32_bf16(a1, b1, acc, 0, 0, 0);
            // C/D layout (verified r2-r6): row = i0+16w+4q+r, col = 16ct+m.
            const int ct = (c << 3) + u;
            unsigned jinv = 1023u - (unsigned)((ct << 4) + m);
#pragma unroll
            for (int r = 0; r < 4; ++r) {
                float e = __builtin_amdgcn_exp2f(acc[r]);   // SCALE folded into At
                unsigned p = (__float_as_uint(e) & 0xFFFFFC00u) | jinv;
                rsum[r] += e;
                if (p > rpk[r]) rpk[r] = p;
            }
        }
        // Orders: (a) chunk c+1's loads complete, (b) all waves done reading
        // buf cur before iteration c+1 re-stages into it.
        __syncthreads();
    }

    // One butterfly over the 16 m-lanes (xor 1,2,4,8) — stats complete.
#pragma unroll
    for (int s = 1; s < 16; s <<= 1) {
#pragma unroll
        for (int r = 0; r < 4; ++r) {
            rsum[r] += __shfl_xor(rsum[r], s, 64);
            unsigned o = (unsigned)__shfl_xor((int)rpk[r], s, 64);
            if (o > rpk[r]) rpk[r] = o;
        }
    }
    if (m == 0) {
#pragma unroll
        for (int r = 0; r < 4; ++r) {
            int idx = (bb << 10) + i0 + 16 * w + 4 * q + r;
            osum[idx] = rsum[r];
            opk[idx]  = rpk[r];
        }
    }
}

// Reference broadcasting: trailing /(sum+EPS) factors are indexed by ELEMENT
// position, not by argmax. Writes per-block partials (no atomics, no init).
__global__ __launch_bounds__(256) void loss_kernel2(
        const float* __restrict__ row_sum, const unsigned* __restrict__ row_pk,
        const float* __restrict__ col_sum, const unsigned* __restrict__ col_pk,
        float* __restrict__ partial) {
    int t = blockIdx.x * 256 + threadIdx.x;
    float acc = 0.f;
#pragma unroll
    for (int it = 0; it < 4; ++it) {
        int p = t + it * 16384;
        if (p < NB * LL) {
            unsigned pk2 = row_pk[p];
            float m2 = __uint_as_float(pk2 & 0xFFFFFC00u);
            int j = 1023 - (int)(pk2 & 1023u);
            float s2 = row_sum[p];
            float s1 = col_sum[p];
            unsigned pk1 = col_pk[(p & ~1023) + j];
            float m1 = __uint_as_float(pk1 & 0xFFFFFC00u);
            acc += logf((m2 / (s2 + EPS)) * (m1 / (s1 + EPS)));
        } else {
            int p2 = p - NB * LL;
            unsigned pk1 = col_pk[p2];
            float m1 = __uint_as_float(pk1 & 0xFFFFFC00u);
            int i = 1023 - (int)(pk1 & 1023u);
            float s1 = col_sum[p2];
            float s2 = row_sum[p2];
            unsigned pk2 = row_pk[(p2 & ~1023) + i];
            float m2 = __uint_as_float(pk2 & 0xFFFFFC00u);
            acc += logf((m1 / (s1 + EPS)) * (m2 / (s2 + EPS)));
        }
    }
#pragma unroll
    for (int off = 32; off > 0; off >>= 1) acc += __shfl_down(acc, off, 64);
    __shared__ float wsum[4];
    int lane = threadIdx.x & 63, w = threadIdx.x >> 6;
    if (lane == 0) wsum[w] = acc;
    __syncthreads();
    if (threadIdx.x == 0)
        partial[blockIdx.x] = wsum[0] + wsum[1] + wsum[2] + wsum[3];
}

__global__ void finalize_kernel(const float* __restrict__ partial,
                                float* __restrict__ out) {
    float v = partial[threadIdx.x];
#pragma unroll
    for (int off = 32; off > 0; off >>= 1) v += __shfl_down(v, off, 64);
    if (threadIdx.x == 0) out[0] = -v / (float)(2 * NB * LL);
}

extern "C" void kernel_launch(void* const* d_in, const int* in_sizes, int n_in,
                              void* d_out, int out_size, void* d_ws, size_t ws_size,
                              hipStream_t stream) {
    const float* rgb = (const float*)d_in[0];
    const float* ir  = (const float*)d_in[1];
    char* wsb = (char*)d_ws;

    __bf16*   At      = (__bf16*)(wsb);
    __bf16*   Bt      = (__bf16*)(wsb + 4194304);
    float*    row_sum = (float*)(wsb + 8388608);
    float*    col_sum = (float*)(wsb + 8519680);
    unsigned* row_pk  = (unsigned*)(wsb + 8650752);
    unsigned* col_pk  = (unsigned*)(wsb + 8781824);
    float*    partial = (float*)(wsb + 8912896);

    transpose_norm_kernel<<<1024, 256, 0, stream>>>(rgb, ir, At, Bt);
    gemm_stats_kernel<<<1024, 256, 0, stream>>>(At, Bt, row_sum, row_pk,
                                                col_sum, col_pk);
    loss_kernel2<<<64, 256, 0, stream>>>(row_sum, row_pk, col_sum, col_pk, partial);
    finalize_kernel<<<1, 64, 0, stream>>>(partial, (float*)d_out);
}